// Round 10
// baseline (265.822 us; speedup 1.0000x reference)
//
#include <hip/hip_runtime.h>
#include <hip/hip_bf16.h>

#define B_    32
#define CIN   128
#define COUT  128
#define NN    128
#define PPAD  130                   // padded p dimension in xT (1 zero col each side)
#define ROWE  (PPAD * CIN)          // 16640 ushorts per padded xT row
#define CHROW 2080                  // 16B chunks per padded row
#define XCH   (4 * CHROW)           // 8320 chunks: 4-row x-tile
#define ACH   512                   // chunks per A slice (4 cslots x 128 o)

typedef __attribute__((ext_vector_type(8))) short short8;
typedef __attribute__((ext_vector_type(4))) float float4v;

static __device__ inline unsigned short f2bf(float f) {
    union { float f; unsigned u; } v; v.f = f;
    unsigned u = v.u;
    unsigned r = u + 0x7FFFu + ((u >> 16) & 1u);   // RNE
    return (unsigned short)(r >> 16);
}

// async 16B global->LDS copy (dest = firstlane base + lane*16; keep issue
// wave-uniform)
static __device__ inline void gll16(const unsigned short* g, unsigned short* l) {
    __builtin_amdgcn_global_load_lds((const __attribute__((address_space(1))) unsigned int*)g,
                                     (__attribute__((address_space(3))) unsigned int*)l,
                                     16, 0, 0);
}

// ---------------------------------------------------------------------------
// x [B][C][N][N] f32 -> xT [B][row][PPAD][128c] bf16, PRE-SWIZZLED:
// 16B chunk at (pp, slot j) holds channels (j ^ (pp&15))*8 .. +7.
// zero cols pp=0,129. One block per (b,row).
// ---------------------------------------------------------------------------
__global__ __launch_bounds__(256) void xpose_kernel(const float* __restrict__ x,
                                                    unsigned short* __restrict__ xT) {
    int b = blockIdx.x >> 7;
    int i = blockIdx.x & 127;
    __shared__ unsigned short tile[CIN * PPAD];   // [c][p], row stride 130
    int tid = threadIdx.x;
    const float* src = x + ((size_t)(b * CIN) * NN + i) * NN;  // x[b][0][i][0]
    #pragma unroll
    for (int e = 0; e < 64; ++e) {
        int idx = e * 256 + tid;
        int c = idx >> 7;
        int p = idx & 127;
        tile[c * PPAD + p] = f2bf(src[(size_t)c * (NN * NN) + p]);
    }
    __syncthreads();
    unsigned short* dst = xT + (size_t)(b * NN + i) * ROWE;
    #pragma unroll
    for (int e = 0; e < 32; ++e) {
        int pi = e * 256 + tid;          // 0..8191
        int c2 = (pi & 63) * 2;
        int p  = pi >> 6;
        ushort2 v;
        v.x = tile[c2 * PPAD + p];
        v.y = tile[(c2 + 1) * PPAD + p];
        int pp = p + 1;
        int sl = (c2 >> 3) ^ (pp & 15);              // baked XOR swizzle
        *(ushort2*)(dst + (size_t)pp * CIN + sl * 8 + (c2 & 7)) = v;
    }
    if (tid < 128) {                                  // zero pad cols
        dst[tid] = 0;
        dst[(size_t)129 * CIN + tid] = 0;
    }
}

// ---------------------------------------------------------------------------
// kernel [O][C][3][3] f32 -> kT2, TRANSPOSED slice layout (bank-conflict-free
// A-reads): slice ph = kd*4+cc (cc = c>>5); within slice chunk pos = o*4+lg
// (lg = (c>>3)&3). Wave A-read -> one contiguous 1024B LDS window.
// ---------------------------------------------------------------------------
__global__ __launch_bounds__(256) void ktrans_kernel(const float* __restrict__ kern,
                                                     unsigned short* __restrict__ kT2) {
    int idx = blockIdx.x * 256 + threadIdx.x;     // 0..147455
    if (idx >= COUT * CIN * 9) return;
    int c  = idx & 127;
    int o  = (idx >> 7) & 127;
    int kd = idx >> 14;                           // 0..8
    int k = kd / 3, d = kd % 3;
    float v = kern[(((size_t)o * CIN + c) * 3 + k) * 3 + d];
    size_t chunk = (size_t)(kd * 4 + (c >> 5)) * ACH + o * 4 + ((c >> 3) & 3);
    kT2[chunk * 8 + (c & 7)] = f2bf(v);
}

// ---------------------------------------------------------------------------
// main v10: block = 2 rows x 128 px x 128 o, 8 waves. Padded x-tile (no edge
// VALU), transposed A slices (conflict-free), 3-buffer A pipeline w/ counted
// vmcnt, x rows 2,3 streamed during phases 0-9, zero-row for borders.
// LDS = 133,120 + 24,576 = 157,696 B. 1 block/CU.
// ---------------------------------------------------------------------------
__global__ __launch_bounds__(512, 2) void conv_mfma10_kernel(
        const unsigned short* __restrict__ xT,
        const unsigned short* __restrict__ kT2,
        const unsigned short* __restrict__ zrow,
        float* __restrict__ out) {
    __shared__ unsigned short xs[(XCH + 3 * ACH) * 8];   // 157,696 B

    // bijective XCD swizzle: 2048 blocks, 8 XCDs, 256-block contiguous slabs
    int wg = blockIdx.x;
    int lb = (wg & 7) * 256 + (wg >> 3);
    int b  = lb >> 6;            // image
    int rp = lb & 63;            // row pair

    int tid  = threadIdx.x;
    int lane = tid & 63;
    int wave = tid >> 6;
    int wo = wave >> 2;            // o half (0/1)
    int wr = (wave >> 1) & 1;      // row of pair
    int wq = wave & 1;             // px 64-half
    int ob  = wo * 64;
    int pb  = wq * 64;
    int l15 = lane & 15;
    int lg  = lane >> 4;           // 0..3

    const unsigned short* xb  = xT + (size_t)b * NN * ROWE;
    const unsigned short* r0s = (rp == 0)  ? zrow : xb + (size_t)(rp * 2 - 1) * ROWE;
    const unsigned short* r1s = xb + (size_t)(rp * 2) * ROWE;
    const unsigned short* r2s = xb + (size_t)(rp * 2 + 1) * ROWE;
    const unsigned short* r3s = (rp == 63) ? zrow : xb + (size_t)(rp * 2 + 2) * ROWE;

    // ---- prologue: x rows 0,1 (5 dup-overlap groups each) + A slices 0,1,2
    {
        #pragma unroll
        for (int g = 0; g < 5; ++g) {
            const int G = (g < 4) ? g * 512 : 1568;
            gll16(r0s + (size_t)(G + tid) * 8, xs + (size_t)(G + tid) * 8);
        }
        #pragma unroll
        for (int g = 0; g < 5; ++g) {
            const int G = (g < 4) ? g * 512 : 1568;
            gll16(r1s + (size_t)(G + tid) * 8, xs + (size_t)(CHROW + G + tid) * 8);
        }
        gll16(kT2 + (size_t)tid * 8,               xs + (size_t)(XCH + tid) * 8);
        gll16(kT2 + (size_t)(ACH + tid) * 8,       xs + (size_t)(XCH + ACH + tid) * 8);
        gll16(kT2 + (size_t)(2 * ACH + tid) * 8,   xs + (size_t)(XCH + 2 * ACH + tid) * 8);
    }
    asm volatile("s_waitcnt vmcnt(1)" ::: "memory");   // rows 0,1 + A0,A1 landed; A2 flying
    __builtin_amdgcn_s_barrier();

    float4v acc[4][4];
    #pragma unroll
    for (int m = 0; m < 4; ++m)
        #pragma unroll
        for (int n = 0; n < 4; ++n)
            acc[m][n] = (float4v)(0.0f);

    short8 aR[2][4], bR[2][4];

    // ---- preload phase-0 fragments (slice 0, kd=0: k=0,d=0, cc=0) ----
    {
        const unsigned short* ab = xs + (size_t)XCH * 8;
        #pragma unroll
        for (int m = 0; m < 4; ++m)
            aR[0][m] = *(const short8*)(ab + ((size_t)(ob + m * 16 + l15) * 4 + lg) * 8);
        const unsigned short* srow = xs + (size_t)wr * ROWE;
        #pragma unroll
        for (int n = 0; n < 4; ++n) {
            int pp = pb + n * 16 + l15;
            bR[0][n] = *(const short8*)(srow + ((size_t)pp * 16 + (lg ^ (pp & 15))) * 8);
        }
    }

    // ---- 36 phases; ph = (kd = ph>>2, cc = ph&3); A buffer = slice % 3 ----
    #pragma unroll
    for (int ph = 0; ph < 36; ++ph) {
        const int q = ph & 1;
        const int pn = (ph + 3 > 35) ? 35 : ph + 3;
        // A-slice issue (phase 0: after MFMA, see below, for prologue-read safety)
        if (ph != 0)
            gll16(kT2 + ((size_t)pn * ACH + tid) * 8,
                  xs + (size_t)(XCH + (pn % 3) * ACH + tid) * 8);
        // stream x rows 2,3 during phases 0..9 (uniform issue counts)
        if (ph <= 4) {
            const int G = (ph < 4) ? ph * 512 : 1568;
            gll16(r2s + (size_t)(G + tid) * 8, xs + (size_t)(2 * CHROW + G + tid) * 8);
        } else if (ph <= 9) {
            const int G = (ph < 9) ? (ph - 5) * 512 : 1568;
            gll16(r3s + (size_t)(G + tid) * 8, xs + (size_t)(3 * CHROW + G + tid) * 8);
        }
        // prefetch next-phase fragments into the other register buffer
        if (ph < 35) {
            const int p1  = ph + 1;
            const int kd1 = p1 >> 2, cc1 = p1 & 3;
            const int k1  = kd1 / 3, d1 = kd1 % 3;
            const unsigned short* ab = xs + (size_t)(XCH + (p1 % 3) * ACH) * 8;
            #pragma unroll
            for (int m = 0; m < 4; ++m)
                aR[q ^ 1][m] = *(const short8*)(ab + ((size_t)(ob + m * 16 + l15) * 4 + lg) * 8);
            const unsigned short* srow = xs + (size_t)(wr + k1) * ROWE;
            #pragma unroll
            for (int n = 0; n < 4; ++n) {
                int pp = pb + n * 16 + l15 + d1;         // 0..129, always valid
                bR[q ^ 1][n] = *(const short8*)(srow +
                    ((size_t)pp * 16 + ((cc1 * 4 + lg) ^ (pp & 15))) * 8);
            }
        }
        __builtin_amdgcn_s_setprio(1);
        #pragma unroll
        for (int m = 0; m < 4; ++m)
            #pragma unroll
            for (int n = 0; n < 4; ++n)
                acc[m][n] = __builtin_amdgcn_mfma_f32_16x16x32_bf16(aR[q][m], bR[q][n], acc[m][n], 0, 0, 0);
        __builtin_amdgcn_s_setprio(0);
        if (ph == 0)   // late issue: keeps prologue slice-0 reads clear of the overwrite
            gll16(kT2 + ((size_t)3 * ACH + tid) * 8,
                  xs + (size_t)(XCH + 0 * ACH + tid) * 8);
        // drain: prefetched LDS reads (so next phase's gll16 can't race them),
        // and all but the newest {1 or 2} gll16s (slice ph+2 must be resident)
        asm volatile("s_waitcnt lgkmcnt(0)" ::: "memory");
        if (ph <= 9) asm volatile("s_waitcnt vmcnt(2)" ::: "memory");
        else         asm volatile("s_waitcnt vmcnt(1)" ::: "memory");
        __builtin_amdgcn_s_barrier();
    }

    // store: D col = lane&15 -> px, row = (lane>>4)*4 + r -> o
    int row = rp * 2 + wr;
    float* op = out + (size_t)b * COUT * NN * NN + (size_t)row * NN;
    #pragma unroll
    for (int m = 0; m < 4; ++m) {
        #pragma unroll
        for (int n = 0; n < 4; ++n) {
            int p = pb + n * 16 + l15;
            #pragma unroll
            for (int r = 0; r < 4; ++r) {
                int o = ob + m * 16 + lg * 4 + r;
                op[(size_t)o * (NN * NN) + p] = acc[m][n][r];
            }
        }
    }
}

// ---------------------------------------------------------------------------
// fallback: naive direct conv (only if workspace too small)
// ---------------------------------------------------------------------------
__global__ __launch_bounds__(256) void conv_naive_kernel(const float* __restrict__ x,
                                                         const float* __restrict__ kern,
                                                         float* __restrict__ out) {
    size_t idx = (size_t)blockIdx.x * 256 + threadIdx.x;
    int p = idx & 127;
    size_t t = idx >> 7;
    int i = t & 127; t >>= 7;
    int o = t & 127;
    int b = (int)(t >> 7);
    float s = 0.f;
    for (int c = 0; c < CIN; ++c) {
        #pragma unroll
        for (int k = 0; k < 3; ++k) {
            int r = i + k - 1;
            if (r < 0 || r >= NN) continue;
            #pragma unroll
            for (int d = 0; d < 3; ++d) {
                int q = p + d - 1;
                if (q < 0 || q >= NN) continue;
                s += kern[(((size_t)o * CIN + c) * 3 + k) * 3 + d]
                   * x[(((size_t)b * CIN + c) * NN + r) * NN + q];
            }
        }
    }
    out[idx] = s;
}

extern "C" void kernel_launch(void* const* d_in, const int* in_sizes, int n_in,
                              void* d_out, int out_size, void* d_ws, size_t ws_size,
                              hipStream_t stream) {
    const float* x    = (const float*)d_in[0];
    const float* kern = (const float*)d_in[1];
    float* out = (float*)d_out;

    const size_t xT_bytes  = (size_t)B_ * NN * ROWE * 2;        // 136,314,880
    const size_t kT_bytes  = (size_t)9 * 4 * ACH * 8 * 2;       //     294,912
    const size_t zr_bytes  = (size_t)CHROW * 16;                //      33,280

    if (ws_size >= xT_bytes + kT_bytes + zr_bytes) {
        unsigned short* xT  = (unsigned short*)d_ws;
        unsigned short* kT2 = (unsigned short*)((char*)d_ws + xT_bytes);
        unsigned short* zr  = (unsigned short*)((char*)d_ws + xT_bytes + kT_bytes);
        hipMemsetAsync(zr, 0, zr_bytes, stream);
        hipLaunchKernelGGL(xpose_kernel, dim3(B_ * NN), dim3(256), 0, stream, x, xT);
        hipLaunchKernelGGL(ktrans_kernel, dim3(576), dim3(256), 0, stream, kern, kT2);
        hipLaunchKernelGGL(conv_mfma10_kernel, dim3(2048), dim3(512), 0, stream, xT, kT2, zr, out);
    } else {
        hipLaunchKernelGGL(conv_naive_kernel, dim3(67108864 / 256), dim3(256), 0, stream,
                           x, kern, out);
    }
}